// Round 1
// baseline (650.057 us; speedup 1.0000x reference)
//
#include <hip/hip_runtime.h>

#define NB 1024
#define NL 512
#define ND 1000   // ATTN
#define NH 1000   // HID

__device__ __forceinline__ void async_copy16(const void* g, void* l) {
    __builtin_amdgcn_global_load_lds(
        (const __attribute__((address_space(1))) void*)g,
        (__attribute__((address_space(3))) void*)l, 16, 0, 0);
}

// -------- Kernel 1: fused scores -> online softmax -> context --------
// One block per b. 256 threads = 4 waves. Chunks of 4 rows (l) staged to LDS
// async (global_load_lds, 16B lanes), double-buffered, counted vmcnt(4).
// Wave w computes row l = 4c + w; per-wave online softmax + context partial;
// flash-combine across the 4 waves at the end.
__global__ __launch_bounds__(256, 4) void attn_pool_kernel(
    const float* __restrict__ ho,          // [NB, NL, ND]
    const unsigned char* __restrict__ mask, // [NB, NL] bool
    const float* __restrict__ Wa_w,        // [ND]
    const float* __restrict__ Wa_b,        // [1]
    float* __restrict__ ctx)               // [NB, ND] out (workspace)
{
    // 2 buffers x 4 rows x 4096B (row padded 4000->4096 so each row = 4x1KB wave loads)
    __shared__ __align__(16) char lbuf[2][4][4096];   // 32768 B
    __shared__ unsigned char msk[NL];
    __shared__ float mArr[4], sArr[4];

    const int b    = blockIdx.x;
    const int tid  = threadIdx.x;
    const int wave = tid >> 6;
    const int lane = tid & 63;

    const unsigned char* mb = mask + (size_t)b * NL;
    // preload masks to LDS (keeps main loop free of extra VMEM ops -> vmcnt counting stays exact)
    msk[tid]       = mb[tid];
    msk[tid + 256] = mb[tid + 256];

    // Wa fragment: lane owns float4 slots lane, lane+64, lane+128, lane+192 (<250)
    float4 wa[4];
    #pragma unroll
    for (int j = 0; j < 4; ++j) {
        int slot = lane + 64 * j;
        wa[j] = (slot < 250) ? ((const float4*)Wa_w)[slot] : make_float4(0.f, 0.f, 0.f, 0.f);
    }
    const float bias = Wa_b[0];

    const char* gb   = (const char*)(ho + (size_t)b * (NL * ND)); // 512 rows x 4000 B
    const char* gend = (const char*)ho + ((size_t)NB * NL * ND) * 4 - 16; // clamp for tail overread

    __syncthreads();  // masks visible; also drains mask loads before counted-vmcnt loop

    // stage chunk (4 rows) into lbuf[sel]; each wave issues exactly 4 loads (k = wave)
    auto stage = [&](int sel, int c) {
        const char* cb = gb + (size_t)c * (4 * 4000);
        char* lb = &lbuf[sel][0][0];
        #pragma unroll
        for (int r = 0; r < 4; ++r) {
            const char* p = cb + r * 4000 + wave * 1024 + lane * 16;
            if (p > gend) p = gend;   // only ever triggers on the tensor's last bytes
            async_copy16((const void*)p, (void*)(lb + r * 4096 + wave * 1024));
        }
    };

    float  m = -1e30f, s = 0.f;
    float4 acc[4];
    #pragma unroll
    for (int j = 0; j < 4; ++j) acc[j] = make_float4(0.f, 0.f, 0.f, 0.f);

    stage(0, 0);

    #pragma unroll 1
    for (int c = 0; c < 128; ++c) {
        if (c + 1 < 128) {
            stage((c + 1) & 1, c + 1);
            asm volatile("s_waitcnt vmcnt(4)" ::: "memory");
        } else {
            asm volatile("s_waitcnt vmcnt(0)" ::: "memory");
        }
        __builtin_amdgcn_sched_barrier(0);
        __builtin_amdgcn_s_barrier();
        __builtin_amdgcn_sched_barrier(0);

        // ---- compute row l = 4c + wave from lbuf[c&1][wave] ----
        const float4* row = (const float4*)&lbuf[c & 1][wave][0];
        float4 v[4];
        float p = 0.f;
        #pragma unroll
        for (int j = 0; j < 4; ++j) {
            int slot = lane + 64 * j;
            v[j] = (slot < 250) ? row[slot] : make_float4(0.f, 0.f, 0.f, 0.f);
            p += v[j].x * wa[j].x + v[j].y * wa[j].y + v[j].z * wa[j].z + v[j].w * wa[j].w;
        }
        #pragma unroll
        for (int off = 32; off > 0; off >>= 1) p += __shfl_xor(p, off, 64);

        int l = 4 * c + wave;
        float sc = p + bias;
        if (msk[l]) sc = -10000.f;

        float mn = fmaxf(m, sc);
        if (mn > m) {                       // wave-uniform branch
            float f = __expf(m - mn);
            s *= f;
            #pragma unroll
            for (int j = 0; j < 4; ++j) {
                acc[j].x *= f; acc[j].y *= f; acc[j].z *= f; acc[j].w *= f;
            }
            m = mn;
        }
        float w = __expf(sc - m);
        s += w;
        #pragma unroll
        for (int j = 0; j < 4; ++j) {
            acc[j].x += w * v[j].x; acc[j].y += w * v[j].y;
            acc[j].z += w * v[j].z; acc[j].w += w * v[j].w;
        }

        __builtin_amdgcn_sched_barrier(0);
        __builtin_amdgcn_s_barrier();
        __builtin_amdgcn_sched_barrier(0);
    }

    // ---- flash-combine the 4 per-wave partials (reuse lbuf as scratch) ----
    float4* cacc4 = (float4*)&lbuf[0][0][0];   // 4 waves x 250 float4 = 16000 B
    #pragma unroll
    for (int j = 0; j < 4; ++j) {
        int slot = lane + 64 * j;
        if (slot < 250) cacc4[wave * 250 + slot] = acc[j];
    }
    if (lane == 0) { mArr[wave] = m; sArr[wave] = s; }
    __syncthreads();

    float gm = fmaxf(fmaxf(mArr[0], mArr[1]), fmaxf(mArr[2], mArr[3]));
    float f0 = __expf(mArr[0] - gm), f1 = __expf(mArr[1] - gm);
    float f2 = __expf(mArr[2] - gm), f3 = __expf(mArr[3] - gm);
    float S  = f0 * sArr[0] + f1 * sArr[1] + f2 * sArr[2] + f3 * sArr[3];
    float inv = 1.0f / S;

    if (tid < 250) {
        float4 a0 = cacc4[tid], a1 = cacc4[250 + tid], a2 = cacc4[500 + tid], a3 = cacc4[750 + tid];
        float4 r;
        r.x = (f0 * a0.x + f1 * a1.x + f2 * a2.x + f3 * a3.x) * inv;
        r.y = (f0 * a0.y + f1 * a1.y + f2 * a2.y + f3 * a3.y) * inv;
        r.z = (f0 * a0.z + f1 * a1.z + f2 * a2.z + f3 * a3.z) * inv;
        r.w = (f0 * a0.w + f1 * a1.w + f2 * a2.w + f3 * a3.w) * inv;
        ((float4*)(ctx + (size_t)b * ND))[tid] = r;
    }
}

// -------- Kernel 2: h = [hc | c] @ Wc_w^T + Wc_b --------
// M=1024, N=1000, K=2000. 64x64 tile, BK=16 (2000 = 125*16), 4x4 micro-tile.
__global__ __launch_bounds__(256, 1) void proj_kernel(
    const float* __restrict__ hc,    // [NB, NH]
    const float* __restrict__ ctx,   // [NB, ND]
    const float* __restrict__ W,     // [NH, NH+ND] row-major
    const float* __restrict__ wb,    // [NH]
    float* __restrict__ out)         // [NB, NH]
{
    __shared__ __align__(16) float Xs[16][68];  // stride 68: float4-aligned rows, ~2-way banks
    __shared__ __align__(16) float Ws[16][68];

    const int tid  = threadIdx.x;
    const int tx   = tid & 15, ty = tid >> 4;
    const int row0 = blockIdx.x * 64;
    const int col0 = blockIdx.y * 64;
    const int jL   = tid & 15;   // k within tile
    const int rL   = tid >> 4;   // row/col within tile (16 per pass)

    float acc[4][4] = {{0.f}};

    for (int kt = 0; kt < 125; ++kt) {
        int kg = kt * 16 + jL;
        #pragma unroll
        for (int p = 0; p < 4; ++p) {
            int r  = rL + p * 16;
            int gr = row0 + r;
            Xs[jL][r] = (kg < NH) ? hc[(size_t)gr * NH + kg]
                                  : ctx[(size_t)gr * ND + (kg - NH)];
            int go = col0 + r;
            Ws[jL][r] = (go < NH) ? W[(size_t)go * (NH + ND) + kg] : 0.f;
        }
        __syncthreads();
        #pragma unroll
        for (int kk = 0; kk < 16; ++kk) {
            float4 xf = *(const float4*)&Xs[kk][ty * 4];
            float4 wf = *(const float4*)&Ws[kk][tx * 4];
            float xr[4] = {xf.x, xf.y, xf.z, xf.w};
            float wr[4] = {wf.x, wf.y, wf.z, wf.w};
            #pragma unroll
            for (int i = 0; i < 4; ++i)
                #pragma unroll
                for (int j = 0; j < 4; ++j)
                    acc[i][j] += xr[i] * wr[j];
        }
        __syncthreads();
    }

    #pragma unroll
    for (int i = 0; i < 4; ++i) {
        int gr = row0 + ty * 4 + i;
        int gc = col0 + tx * 4;
        if (gc < NH) {
            float4 o;
            o.x = acc[i][0] + wb[gc + 0];
            o.y = acc[i][1] + wb[gc + 1];
            o.z = acc[i][2] + wb[gc + 2];
            o.w = acc[i][3] + wb[gc + 3];
            *(float4*)&out[(size_t)gr * NH + gc] = o;
        }
    }
}

extern "C" void kernel_launch(void* const* d_in, const int* in_sizes, int n_in,
                              void* d_out, int out_size, void* d_ws, size_t ws_size,
                              hipStream_t stream) {
    const float* hc           = (const float*)d_in[0];
    const float* ho           = (const float*)d_in[1];
    const unsigned char* mask = (const unsigned char*)d_in[2];
    const float* Wa_w         = (const float*)d_in[3];
    const float* Wa_b         = (const float*)d_in[4];
    const float* Wc_w         = (const float*)d_in[5];
    const float* Wc_b         = (const float*)d_in[6];
    float* out = (float*)d_out;
    float* ctx = (float*)d_ws;   // NB*ND floats = 4.096 MB scratch

    attn_pool_kernel<<<NB, 256, 0, stream>>>(ho, mask, Wa_w, Wa_b, ctx);
    proj_kernel<<<dim3(NB / 64, 16), 256, 0, stream>>>(hc, ctx, Wc_w, Wc_b, out);
}

// Round 2
// 431.514 us; speedup vs baseline: 1.5065x; 1.5065x over previous
//
#include <hip/hip_runtime.h>

#define NB 1024
#define NL 512
#define ND 1000   // ATTN
#define NH 1000   // HID

__device__ __forceinline__ void async_copy16(const void* g, void* l) {
    __builtin_amdgcn_global_load_lds(
        (const __attribute__((address_space(1))) void*)g,
        (__attribute__((address_space(3))) void*)l, 16, 0, 0);
}

// -------- Kernel 1: fused scores -> online softmax -> context --------
// One block per b, 4 waves. Barrier-free main loop: wave w owns rows 4c+w and
// stages them into its PRIVATE LDS double-buffer (4x 1KB global_load_lds per
// row), per-wave counted vmcnt(4). No cross-wave sync until the final
// flash-combine of the 4 per-wave partials.
__global__ __launch_bounds__(256, 4) void attn_pool_kernel(
    const float* __restrict__ ho,           // [NB, NL, ND]
    const unsigned char* __restrict__ mask, // [NB, NL]
    const float* __restrict__ Wa_w,         // [ND]
    const float* __restrict__ Wa_b,         // [1]
    float* __restrict__ ctx)                // [NB, ND] out (workspace)
{
    __shared__ __align__(16) char lbuf[4][2][4096];   // [wave][buf][row 4000->4096]
    __shared__ unsigned char msk[NL];
    __shared__ float mArr[4], sArr[4];

    const int b    = blockIdx.x;
    const int tid  = threadIdx.x;
    const int wave = tid >> 6;
    const int lane = tid & 63;

    const unsigned char* mb = mask + (size_t)b * NL;
    msk[tid]       = mb[tid];
    msk[tid + 256] = mb[tid + 256];

    // Wa fragment: lane owns float4 slots lane, lane+64, lane+128, lane+192 (<250)
    float4 wa[4];
    #pragma unroll
    for (int j = 0; j < 4; ++j) {
        int slot = lane + 64 * j;
        wa[j] = (slot < 250) ? ((const float4*)Wa_w)[slot] : make_float4(0.f, 0.f, 0.f, 0.f);
    }
    const float bias = Wa_b[0];

    const char* gb   = (const char*)(ho + (size_t)b * (NL * ND)); // 512 rows x 4000 B
    const char* gend = (const char*)ho + ((size_t)NB * NL * ND) * 4 - 16;

    __syncthreads();  // masks visible; drains mask-load vmcnt before counted region

    auto stageRow = [&](int d, int l) {
        const char* rp = gb + (size_t)l * 4000;
        char* lb = &lbuf[wave][d][0];
        #pragma unroll
        for (int s4 = 0; s4 < 4; ++s4) {
            const char* p = rp + s4 * 1024 + lane * 16;
            if (p > gend) p = gend;     // clamp only at tensor tail
            async_copy16((const void*)p, (void*)(lb + s4 * 1024));
        }
    };

    float  m = -1e30f, s = 0.f;
    float4 acc[4];
    #pragma unroll
    for (int j = 0; j < 4; ++j) acc[j] = make_float4(0.f, 0.f, 0.f, 0.f);

    stageRow(0, wave);   // row for c=0

    #pragma unroll 1
    for (int c = 0; c < 128; ++c) {
        if (c + 1 < 128) {
            stageRow((c + 1) & 1, 4 * (c + 1) + wave);
            asm volatile("s_waitcnt vmcnt(4)" ::: "memory");  // row c staged
        } else {
            asm volatile("s_waitcnt vmcnt(0)" ::: "memory");
        }
        __builtin_amdgcn_sched_barrier(0);

        const float4* row = (const float4*)&lbuf[wave][c & 1][0];
        float4 v[4];
        float p = 0.f;
        #pragma unroll
        for (int j = 0; j < 4; ++j) {
            int slot = lane + 64 * j;
            v[j] = (slot < 250) ? row[slot] : make_float4(0.f, 0.f, 0.f, 0.f);
            p += v[j].x * wa[j].x + v[j].y * wa[j].y + v[j].z * wa[j].z + v[j].w * wa[j].w;
        }
        #pragma unroll
        for (int off = 32; off > 0; off >>= 1) p += __shfl_xor(p, off, 64);

        int l = 4 * c + wave;
        float sc = p + bias;
        if (msk[l]) sc = -10000.f;

        float mn = fmaxf(m, sc);
        if (mn > m) {                       // wave-uniform branch
            float f = __expf(m - mn);
            s *= f;
            #pragma unroll
            for (int j = 0; j < 4; ++j) {
                acc[j].x *= f; acc[j].y *= f; acc[j].z *= f; acc[j].w *= f;
            }
            m = mn;
        }
        float w = __expf(sc - m);
        s += w;
        #pragma unroll
        for (int j = 0; j < 4; ++j) {
            acc[j].x += w * v[j].x; acc[j].y += w * v[j].y;
            acc[j].z += w * v[j].z; acc[j].w += w * v[j].w;
        }
        __builtin_amdgcn_sched_barrier(0);  // pin: next stage can't hoist above compute
    }

    __syncthreads();   // all waves done with private bufs before scratch reuse

    // ---- flash-combine the 4 per-wave partials (reuse lbuf as scratch) ----
    float4* cacc4 = (float4*)&lbuf[0][0][0];   // 4 x 250 float4 = 16000 B
    #pragma unroll
    for (int j = 0; j < 4; ++j) {
        int slot = lane + 64 * j;
        if (slot < 250) cacc4[wave * 250 + slot] = acc[j];
    }
    if (lane == 0) { mArr[wave] = m; sArr[wave] = s; }
    __syncthreads();

    float gm = fmaxf(fmaxf(mArr[0], mArr[1]), fmaxf(mArr[2], mArr[3]));
    float f0 = __expf(mArr[0] - gm), f1 = __expf(mArr[1] - gm);
    float f2 = __expf(mArr[2] - gm), f3 = __expf(mArr[3] - gm);
    float S  = f0 * sArr[0] + f1 * sArr[1] + f2 * sArr[2] + f3 * sArr[3];
    float inv = 1.0f / S;

    if (tid < 250) {
        float4 a0 = cacc4[tid], a1 = cacc4[250 + tid], a2 = cacc4[500 + tid], a3 = cacc4[750 + tid];
        float4 r;
        r.x = (f0 * a0.x + f1 * a1.x + f2 * a2.x + f3 * a3.x) * inv;
        r.y = (f0 * a0.y + f1 * a1.y + f2 * a2.y + f3 * a3.y) * inv;
        r.z = (f0 * a0.z + f1 * a1.z + f2 * a2.z + f3 * a3.z) * inv;
        r.w = (f0 * a0.w + f1 * a1.w + f2 * a2.w + f3 * a3.w) * inv;
        ((float4*)(ctx + (size_t)b * ND))[tid] = r;
    }
}

// -------- Kernel 2a: K-split GEMM partials --------
// partial[ks][b][j] = sum_{k in slice ks} X[b][k] * W[j][k]
// grid (16,16,4) = 1024 blocks = 4/CU (16 waves/CU). 64x64 tile, BK=16,
// KSLICE=500 (32 kt iters, last partially masked). Register prefetch of the
// next K-tile overlaps global latency with the FMA phase.
#define KS     4
#define KSLICE 500
#define KT     32   // ceil(500/16)

__global__ __launch_bounds__(256, 4) void proj_partial_kernel(
    const float* __restrict__ hc,    // [NB, NH]
    const float* __restrict__ ctx,   // [NB, ND]
    const float* __restrict__ W,     // [NH, NH+ND]
    float* __restrict__ partial)     // [KS, NB, NH]
{
    __shared__ __align__(16) float Xs[16][68];
    __shared__ __align__(16) float Ws[16][68];

    const int tid  = threadIdx.x;
    const int tx   = tid & 15, ty = tid >> 4;
    const int jL   = tid & 15, rL = tid >> 4;
    const int row0 = blockIdx.x * 64;
    const int col0 = blockIdx.y * 64;
    const int k0   = blockIdx.z * KSLICE;

    float acc[4][4] = {{0.f}};

    auto gload = [&](int kt, float* xr, float* wr) {
        int kin = kt * 16 + jL;
        bool ok = kin < KSLICE;
        int kg  = k0 + kin;
        #pragma unroll
        for (int p = 0; p < 4; ++p) {
            int r  = rL + p * 16;
            int gr = row0 + r;
            int go = col0 + r;
            float xv = 0.f, wv = 0.f;
            if (ok) {
                xv = (kg < NH) ? hc[(size_t)gr * NH + kg]
                               : ctx[(size_t)gr * ND + (kg - NH)];
                wv = (go < NH) ? W[(size_t)go * (NH + ND) + kg] : 0.f;
            }
            xr[p] = xv; wr[p] = wv;
        }
    };

    float xr_[4], wr_[4];
    gload(0, xr_, wr_);

    #pragma unroll 1
    for (int kt = 0; kt < KT; ++kt) {
        #pragma unroll
        for (int p = 0; p < 4; ++p) {
            Xs[jL][rL + p * 16] = xr_[p];
            Ws[jL][rL + p * 16] = wr_[p];
        }
        __syncthreads();

        float xn[4], wn[4];
        if (kt + 1 < KT) gload(kt + 1, xn, wn);   // overlap with compute below

        #pragma unroll
        for (int kk = 0; kk < 16; ++kk) {
            float4 xf = *(const float4*)&Xs[kk][ty * 4];
            float4 wf = *(const float4*)&Ws[kk][tx * 4];
            float xq[4] = {xf.x, xf.y, xf.z, xf.w};
            float wq[4] = {wf.x, wf.y, wf.z, wf.w};
            #pragma unroll
            for (int i = 0; i < 4; ++i)
                #pragma unroll
                for (int j = 0; j < 4; ++j)
                    acc[i][j] += xq[i] * wq[j];
        }
        __syncthreads();

        #pragma unroll
        for (int p = 0; p < 4; ++p) { xr_[p] = xn[p]; wr_[p] = wn[p]; }
    }

    float* pbase = partial + (size_t)blockIdx.z * NB * NH;
    #pragma unroll
    for (int i = 0; i < 4; ++i) {
        int gr = row0 + ty * 4 + i;
        int gc = col0 + tx * 4;
        if (gc < NH) {
            float4 o = make_float4(acc[i][0], acc[i][1], acc[i][2], acc[i][3]);
            *(float4*)&pbase[(size_t)gr * NH + gc] = o;
        }
    }
}

// -------- Kernel 2b: reduce partials + bias --------
__global__ __launch_bounds__(256) void proj_reduce_kernel(
    const float* __restrict__ partial,  // [KS, NB, NH]
    const float* __restrict__ wb,       // [NH]
    float* __restrict__ out)            // [NB, NH]
{
    int idx = blockIdx.x * 256 + threadIdx.x;    // over NB*250 float4 slots
    if (idx >= NB * 250) return;
    int bb = idx / 250, j4 = idx - bb * 250;

    float4 r = ((const float4*)wb)[j4];
    #pragma unroll
    for (int s = 0; s < KS; ++s) {
        float4 p = *(const float4*)&partial[((size_t)s * NB + bb) * NH + j4 * 4];
        r.x += p.x; r.y += p.y; r.z += p.z; r.w += p.w;
    }
    *(float4*)&out[(size_t)bb * NH + j4 * 4] = r;
}

extern "C" void kernel_launch(void* const* d_in, const int* in_sizes, int n_in,
                              void* d_out, int out_size, void* d_ws, size_t ws_size,
                              hipStream_t stream) {
    const float* hc           = (const float*)d_in[0];
    const float* ho           = (const float*)d_in[1];
    const unsigned char* mask = (const unsigned char*)d_in[2];
    const float* Wa_w         = (const float*)d_in[3];
    const float* Wa_b         = (const float*)d_in[4];
    const float* Wc_w         = (const float*)d_in[5];
    const float* Wc_b         = (const float*)d_in[6];
    float* out = (float*)d_out;

    float* ctx     = (float*)d_ws;                      // NB*ND f32 = 4.10 MB
    float* partial = (float*)d_ws + (size_t)NB * ND;    // KS*NB*NH f32 = 16.4 MB

    attn_pool_kernel<<<NB, 256, 0, stream>>>(ho, mask, Wa_w, Wa_b, ctx);
    proj_partial_kernel<<<dim3(16, 16, KS), 256, 0, stream>>>(hc, ctx, Wc_w, partial);
    proj_reduce_kernel<<<(NB * 250 + 255) / 256, 256, 0, stream>>>(partial, Wc_b, out);
}

// Round 3
// 387.976 us; speedup vs baseline: 1.6755x; 1.1122x over previous
//
#include <hip/hip_runtime.h>

#define NB 1024
#define NL 512
#define ND 1000   // ATTN
#define NH 1000   // HID
#define KP 2048   // padded K (= NH + ND padded to 2048)

typedef __attribute__((ext_vector_type(8))) short bf16x8;
typedef __attribute__((ext_vector_type(4))) float f32x4;

__device__ __forceinline__ unsigned short f2bf(float f) {
    unsigned u = __float_as_uint(f);
    u += 0x7FFFu + ((u >> 16) & 1u);     // RNE
    return (unsigned short)(u >> 16);
}

__device__ __forceinline__ void async_copy16(const void* g, void* l) {
    __builtin_amdgcn_global_load_lds(
        (const __attribute__((address_space(1))) void*)g,
        (__attribute__((address_space(3))) void*)l, 16, 0, 0);
}

// -------- Kernel 0: prep — convert hc and Wc_w to bf16 (padded) --------
// blocks [0,NB): Xb row b cols 0..999 from hc, cols 2000..2047 zero
// blocks [NB, NB+1024): Wb row n (cols from W for n<NH, zero-pad otherwise)
__global__ __launch_bounds__(256) void prep_kernel(
    const float* __restrict__ hc, const float* __restrict__ W,
    unsigned short* __restrict__ Xb, unsigned short* __restrict__ Wb)
{
    const int bid = blockIdx.x, t = threadIdx.x;
    if (bid < NB) {
        ushort4* xq = (ushort4*)(Xb + (size_t)bid * KP);
        if (t < 250) {
            float4 v = ((const float4*)(hc + (size_t)bid * NH))[t];
            xq[t] = make_ushort4(f2bf(v.x), f2bf(v.y), f2bf(v.z), f2bf(v.w));
        } else if (t < 262) {
            xq[500 + (t - 250)] = make_ushort4(0, 0, 0, 0);
        }
    } else {
        const int n = bid - NB;
        ushort4* wq = (ushort4*)(Wb + (size_t)n * KP);
        if (n < NH) {
            #pragma unroll
            for (int rep = 0; rep < 2; ++rep) {
                int q = t + rep * 256;
                if (q < 500) {
                    float4 v = ((const float4*)(W + (size_t)n * (NH + ND)))[q];
                    wq[q] = make_ushort4(f2bf(v.x), f2bf(v.y), f2bf(v.z), f2bf(v.w));
                } else {
                    wq[q] = make_ushort4(0, 0, 0, 0);
                }
            }
        } else {
            wq[t]       = make_ushort4(0, 0, 0, 0);
            wq[t + 256] = make_ushort4(0, 0, 0, 0);
        }
    }
}

// -------- Kernel 1: fused scores -> online softmax -> context --------
// Unchanged structure (control). Epilogue now writes ctx as bf16 into
// Xb[b][1000..1999].
__global__ __launch_bounds__(256, 4) void attn_pool_kernel(
    const float* __restrict__ ho,           // [NB, NL, ND]
    const unsigned char* __restrict__ mask, // [NB, NL]
    const float* __restrict__ Wa_w,         // [ND]
    const float* __restrict__ Wa_b,         // [1]
    unsigned short* __restrict__ Xb)        // [NB, KP] bf16, cols 1000..1999
{
    __shared__ __align__(16) char lbuf[4][2][4096];   // [wave][buf][row 4000->4096]
    __shared__ unsigned char msk[NL];
    __shared__ float mArr[4], sArr[4];

    const int b    = blockIdx.x;
    const int tid  = threadIdx.x;
    const int wave = tid >> 6;
    const int lane = tid & 63;

    const unsigned char* mb = mask + (size_t)b * NL;
    msk[tid]       = mb[tid];
    msk[tid + 256] = mb[tid + 256];

    float4 wa[4];
    #pragma unroll
    for (int j = 0; j < 4; ++j) {
        int slot = lane + 64 * j;
        wa[j] = (slot < 250) ? ((const float4*)Wa_w)[slot] : make_float4(0.f, 0.f, 0.f, 0.f);
    }
    const float bias = Wa_b[0];

    const char* gb   = (const char*)(ho + (size_t)b * (NL * ND)); // 512 rows x 4000 B
    const char* gend = (const char*)ho + ((size_t)NB * NL * ND) * 4 - 16;

    __syncthreads();  // masks visible; drains mask-load vmcnt before counted region

    auto stageRow = [&](int d, int l) {
        const char* rp = gb + (size_t)l * 4000;
        char* lb = &lbuf[wave][d][0];
        #pragma unroll
        for (int s4 = 0; s4 < 4; ++s4) {
            const char* p = rp + s4 * 1024 + lane * 16;
            if (p > gend) p = gend;     // clamp only at tensor tail
            async_copy16((const void*)p, (void*)(lb + s4 * 1024));
        }
    };

    float  m = -1e30f, s = 0.f;
    float4 acc[4];
    #pragma unroll
    for (int j = 0; j < 4; ++j) acc[j] = make_float4(0.f, 0.f, 0.f, 0.f);

    stageRow(0, wave);

    #pragma unroll 1
    for (int c = 0; c < 128; ++c) {
        if (c + 1 < 128) {
            stageRow((c + 1) & 1, 4 * (c + 1) + wave);
            asm volatile("s_waitcnt vmcnt(4)" ::: "memory");
        } else {
            asm volatile("s_waitcnt vmcnt(0)" ::: "memory");
        }
        __builtin_amdgcn_sched_barrier(0);

        const float4* row = (const float4*)&lbuf[wave][c & 1][0];
        float4 v[4];
        float p = 0.f;
        #pragma unroll
        for (int j = 0; j < 4; ++j) {
            int slot = lane + 64 * j;
            v[j] = (slot < 250) ? row[slot] : make_float4(0.f, 0.f, 0.f, 0.f);
            p += v[j].x * wa[j].x + v[j].y * wa[j].y + v[j].z * wa[j].z + v[j].w * wa[j].w;
        }
        #pragma unroll
        for (int off = 32; off > 0; off >>= 1) p += __shfl_xor(p, off, 64);

        int l = 4 * c + wave;
        float sc = p + bias;
        if (msk[l]) sc = -10000.f;

        float mn = fmaxf(m, sc);
        if (mn > m) {
            float f = __expf(m - mn);
            s *= f;
            #pragma unroll
            for (int j = 0; j < 4; ++j) {
                acc[j].x *= f; acc[j].y *= f; acc[j].z *= f; acc[j].w *= f;
            }
            m = mn;
        }
        float w = __expf(sc - m);
        s += w;
        #pragma unroll
        for (int j = 0; j < 4; ++j) {
            acc[j].x += w * v[j].x; acc[j].y += w * v[j].y;
            acc[j].z += w * v[j].z; acc[j].w += w * v[j].w;
        }
        __builtin_amdgcn_sched_barrier(0);
    }

    __syncthreads();

    float4* cacc4 = (float4*)&lbuf[0][0][0];   // 4 x 250 float4
    #pragma unroll
    for (int j = 0; j < 4; ++j) {
        int slot = lane + 64 * j;
        if (slot < 250) cacc4[wave * 250 + slot] = acc[j];
    }
    if (lane == 0) { mArr[wave] = m; sArr[wave] = s; }
    __syncthreads();

    float gm = fmaxf(fmaxf(mArr[0], mArr[1]), fmaxf(mArr[2], mArr[3]));
    float f0 = __expf(mArr[0] - gm), f1 = __expf(mArr[1] - gm);
    float f2 = __expf(mArr[2] - gm), f3 = __expf(mArr[3] - gm);
    float S  = f0 * sArr[0] + f1 * sArr[1] + f2 * sArr[2] + f3 * sArr[3];
    float inv = 1.0f / S;

    if (tid < 250) {
        float4 a0 = cacc4[tid], a1 = cacc4[250 + tid], a2 = cacc4[500 + tid], a3 = cacc4[750 + tid];
        float4 r;
        r.x = (f0 * a0.x + f1 * a1.x + f2 * a2.x + f3 * a3.x) * inv;
        r.y = (f0 * a0.y + f1 * a1.y + f2 * a2.y + f3 * a3.y) * inv;
        r.z = (f0 * a0.z + f1 * a1.z + f2 * a2.z + f3 * a3.z) * inv;
        r.w = (f0 * a0.w + f1 * a1.w + f2 * a2.w + f3 * a3.w) * inv;
        ((ushort4*)(Xb + (size_t)b * KP + ND))[tid] =
            make_ushort4(f2bf(r.x), f2bf(r.y), f2bf(r.z), f2bf(r.w));
    }
}

// -------- Kernel 2: bf16 MFMA projection: out = Xb @ Wb^T + bias --------
// 64x64 tile per block, grid 16x16 (1 block/CU). 4 waves each own a K-slice
// of 512 (16 k-steps of 32); acc 4x4 frags of 16x16x32; register-prefetched
// fragments loaded directly from global (L2/L3-resident). Cross-wave LDS
// reduce + bias in epilogue.
__global__ __launch_bounds__(256, 1) void mfma_proj_kernel(
    const unsigned short* __restrict__ Xb,   // [NB][KP] bf16
    const unsigned short* __restrict__ Wb,   // [1024][KP] bf16
    const float* __restrict__ wb,            // [NH]
    float* __restrict__ out)                 // [NB][NH]
{
    __shared__ float red[64][65];

    const int tid  = threadIdx.x;
    const int wave = tid >> 6;
    const int lane = tid & 63;
    const int row0 = blockIdx.x * 64;
    const int col0 = blockIdx.y * 64;
    const int r    = lane & 15;    // A-row / B-col within fragment
    const int g    = lane >> 4;    // k-chunk (8 bf16)

    const int kbase = wave * 512 + g * 8;
    const unsigned short* xp = Xb + (size_t)(row0 + r) * KP + kbase;
    const unsigned short* wp = Wb + (size_t)(col0 + r) * KP + kbase;

    f32x4 acc[4][4];
    #pragma unroll
    for (int mi = 0; mi < 4; ++mi)
        #pragma unroll
        for (int ni = 0; ni < 4; ++ni)
            acc[mi][ni] = (f32x4){0.f, 0.f, 0.f, 0.f};

    bf16x8 a_[4], b_[4], an[4], bn[4];
    #pragma unroll
    for (int i = 0; i < 4; ++i) {
        a_[i] = *(const bf16x8*)(xp + (size_t)i * 16 * KP);
        b_[i] = *(const bf16x8*)(wp + (size_t)i * 16 * KP);
    }

    #pragma unroll 1
    for (int ks = 0; ks < 16; ++ks) {
        if (ks + 1 < 16) {
            const unsigned short* xq = xp + (ks + 1) * 32;
            const unsigned short* wq = wp + (ks + 1) * 32;
            #pragma unroll
            for (int i = 0; i < 4; ++i) {
                an[i] = *(const bf16x8*)(xq + (size_t)i * 16 * KP);
                bn[i] = *(const bf16x8*)(wq + (size_t)i * 16 * KP);
            }
        }
        #pragma unroll
        for (int mi = 0; mi < 4; ++mi)
            #pragma unroll
            for (int ni = 0; ni < 4; ++ni)
                acc[mi][ni] = __builtin_amdgcn_mfma_f32_16x16x32_bf16(
                    a_[mi], b_[ni], acc[mi][ni], 0, 0, 0);
        #pragma unroll
        for (int i = 0; i < 4; ++i) { a_[i] = an[i]; b_[i] = bn[i]; }
    }

    // ---- cross-wave reduce (serialized, 4 phases) ----
    #pragma unroll
    for (int w = 0; w < 4; ++w) {
        if (wave == w) {
            #pragma unroll
            for (int mi = 0; mi < 4; ++mi)
                #pragma unroll
                for (int ni = 0; ni < 4; ++ni)
                    #pragma unroll
                    for (int j = 0; j < 4; ++j) {
                        int rr = mi * 16 + g * 4 + j;   // C/D: row=(lane>>4)*4+reg
                        int cc = ni * 16 + r;           // C/D: col=lane&15
                        float v = acc[mi][ni][j];
                        if (w == 0) red[rr][cc] = v;
                        else        red[rr][cc] += v;
                    }
        }
        __syncthreads();
    }

    // ---- store + bias ----
    const int cc = tid & 63;
    const int rg = tid >> 6;
    const int gc = col0 + cc;
    if (gc < NH) {
        float bias = wb[gc];
        #pragma unroll
        for (int i = 0; i < 16; ++i) {
            int rr = rg * 16 + i;
            out[(size_t)(row0 + rr) * NH + gc] = red[rr][cc] + bias;
        }
    }
}

extern "C" void kernel_launch(void* const* d_in, const int* in_sizes, int n_in,
                              void* d_out, int out_size, void* d_ws, size_t ws_size,
                              hipStream_t stream) {
    const float* hc           = (const float*)d_in[0];
    const float* ho           = (const float*)d_in[1];
    const unsigned char* mask = (const unsigned char*)d_in[2];
    const float* Wa_w         = (const float*)d_in[3];
    const float* Wa_b         = (const float*)d_in[4];
    const float* Wc_w         = (const float*)d_in[5];
    const float* Wc_b         = (const float*)d_in[6];
    float* out = (float*)d_out;

    unsigned short* Xb = (unsigned short*)d_ws;                       // 1024*2048 bf16 = 4 MB
    unsigned short* Wb = (unsigned short*)d_ws + (size_t)NB * KP;     // 1024*2048 bf16 = 4 MB

    prep_kernel<<<2048, 256, 0, stream>>>(hc, Wc_w, Xb, Wb);
    attn_pool_kernel<<<NB, 256, 0, stream>>>(ho, mask, Wa_w, Wa_b, Xb);
    mfma_proj_kernel<<<dim3(16, 16), 256, 0, stream>>>(Xb, Wb, Wc_b, out);
}

// Round 4
// 386.695 us; speedup vs baseline: 1.6811x; 1.0033x over previous
//
#include <hip/hip_runtime.h>

#define NB 1024
#define NL 512
#define ND 1000   // ATTN
#define NH 1000   // HID
#define KP 2048   // padded K (= NH + ND padded to 2048)

typedef __attribute__((ext_vector_type(8))) short bf16x8;
typedef __attribute__((ext_vector_type(4))) float f32x4;

__device__ __forceinline__ unsigned short f2bf(float f) {
    unsigned u = __float_as_uint(f);
    u += 0x7FFFu + ((u >> 16) & 1u);     // RNE
    return (unsigned short)(u >> 16);
}

// -------- Kernel 0: prep — convert hc and Wc_w to bf16 (padded) --------
__global__ __launch_bounds__(256) void prep_kernel(
    const float* __restrict__ hc, const float* __restrict__ W,
    unsigned short* __restrict__ Xb, unsigned short* __restrict__ Wb)
{
    const int bid = blockIdx.x, t = threadIdx.x;
    if (bid < NB) {
        ushort4* xq = (ushort4*)(Xb + (size_t)bid * KP);
        if (t < 250) {
            float4 v = ((const float4*)(hc + (size_t)bid * NH))[t];
            xq[t] = make_ushort4(f2bf(v.x), f2bf(v.y), f2bf(v.z), f2bf(v.w));
        } else if (t < 262) {
            xq[500 + (t - 250)] = make_ushort4(0, 0, 0, 0);
        }
    } else {
        const int n = bid - NB;
        ushort4* wq = (ushort4*)(Wb + (size_t)n * KP);
        if (n < NH) {
            #pragma unroll
            for (int rep = 0; rep < 2; ++rep) {
                int q = t + rep * 256;
                if (q < 500) {
                    float4 v = ((const float4*)(W + (size_t)n * (NH + ND)))[q];
                    wq[q] = make_ushort4(f2bf(v.x), f2bf(v.y), f2bf(v.z), f2bf(v.w));
                } else {
                    wq[q] = make_ushort4(0, 0, 0, 0);
                }
            }
        } else {
            wq[t]       = make_ushort4(0, 0, 0, 0);
            wq[t + 256] = make_ushort4(0, 0, 0, 0);
        }
    }
}

// -------- Kernel 1: fused scores -> online softmax -> context --------
// One block per b, 4 waves. NO LDS staging: wave w reads row 4c+w directly
// into registers (4 predicated float4/lane, slots lane+64j < 250), with a
// depth-2 register prefetch pipeline (rows c+1, c+2 in flight). No barriers
// in the main loop; compiler-managed waitcnt. LDS only for masks + the final
// flash-combine scratch (16.6 KB).
__global__ __launch_bounds__(256, 4) void attn_pool_kernel(
    const float* __restrict__ ho,           // [NB, NL, ND]
    const unsigned char* __restrict__ mask, // [NB, NL]
    const float* __restrict__ Wa_w,         // [ND]
    const float* __restrict__ Wa_b,         // [1]
    unsigned short* __restrict__ Xb)        // [NB, KP] bf16, cols 1000..1999
{
    __shared__ __align__(16) float cacc[4][ND];   // 16000 B combine scratch
    __shared__ unsigned char msk[NL];
    __shared__ float mArr[4], sArr[4];

    const int b    = blockIdx.x;
    const int tid  = threadIdx.x;
    const int wave = tid >> 6;
    const int lane = tid & 63;

    const unsigned char* mb = mask + (size_t)b * NL;
    msk[tid]       = mb[tid];
    msk[tid + 256] = mb[tid + 256];

    // Wa fragment: lane owns float4 slots lane, lane+64, lane+128, lane+192 (<250)
    float4 wa[4];
    #pragma unroll
    for (int j = 0; j < 4; ++j) {
        int slot = lane + 64 * j;
        wa[j] = (slot < 250) ? ((const float4*)Wa_w)[slot] : make_float4(0.f, 0.f, 0.f, 0.f);
    }
    const float bias = Wa_b[0];

    const float4* hob = (const float4*)(ho + (size_t)b * NL * ND);  // rows of 250 float4

    __syncthreads();  // masks visible

    auto loadRow = [&](int l, float4* v) {
        const float4* rp = hob + (size_t)l * 250;
        #pragma unroll
        for (int j = 0; j < 3; ++j) v[j] = rp[lane + 64 * j];
        v[3] = (lane < 58) ? rp[lane + 192] : make_float4(0.f, 0.f, 0.f, 0.f);
    };

    float  m = -1e30f, s = 0.f;
    float4 acc[4];
    #pragma unroll
    for (int j = 0; j < 4; ++j) acc[j] = make_float4(0.f, 0.f, 0.f, 0.f);

    float4 cur[4], nx1[4], nx2[4];
    loadRow(wave, cur);
    loadRow(4 + wave, nx1);

    #pragma unroll 2
    for (int c = 0; c < 128; ++c) {
        if (c + 2 < 128) loadRow(4 * (c + 2) + wave, nx2);

        float p = 0.f;
        #pragma unroll
        for (int j = 0; j < 4; ++j)
            p += cur[j].x * wa[j].x + cur[j].y * wa[j].y +
                 cur[j].z * wa[j].z + cur[j].w * wa[j].w;
        #pragma unroll
        for (int off = 32; off > 0; off >>= 1) p += __shfl_xor(p, off, 64);

        int l = 4 * c + wave;
        float sc = p + bias;
        if (msk[l]) sc = -10000.f;

        float mn = fmaxf(m, sc);
        if (mn > m) {                       // wave-uniform branch
            float f = __expf(m - mn);
            s *= f;
            #pragma unroll
            for (int j = 0; j < 4; ++j) {
                acc[j].x *= f; acc[j].y *= f; acc[j].z *= f; acc[j].w *= f;
            }
            m = mn;
        }
        float w = __expf(sc - m);
        s += w;
        #pragma unroll
        for (int j = 0; j < 4; ++j) {
            acc[j].x += w * cur[j].x; acc[j].y += w * cur[j].y;
            acc[j].z += w * cur[j].z; acc[j].w += w * cur[j].w;
        }

        #pragma unroll
        for (int j = 0; j < 4; ++j) { cur[j] = nx1[j]; nx1[j] = nx2[j]; }
    }

    // ---- flash-combine the 4 per-wave partials ----
    float4* cw = (float4*)&cacc[wave][0];   // 250 float4 per wave
    #pragma unroll
    for (int j = 0; j < 4; ++j) {
        int slot = lane + 64 * j;
        if (slot < 250) cw[slot] = acc[j];
    }
    if (lane == 0) { mArr[wave] = m; sArr[wave] = s; }
    __syncthreads();

    float gm = fmaxf(fmaxf(mArr[0], mArr[1]), fmaxf(mArr[2], mArr[3]));
    float f0 = __expf(mArr[0] - gm), f1 = __expf(mArr[1] - gm);
    float f2 = __expf(mArr[2] - gm), f3 = __expf(mArr[3] - gm);
    float S  = f0 * sArr[0] + f1 * sArr[1] + f2 * sArr[2] + f3 * sArr[3];
    float inv = 1.0f / S;

    if (tid < 250) {
        float4 a0 = ((float4*)&cacc[0][0])[tid];
        float4 a1 = ((float4*)&cacc[1][0])[tid];
        float4 a2 = ((float4*)&cacc[2][0])[tid];
        float4 a3 = ((float4*)&cacc[3][0])[tid];
        float4 r;
        r.x = (f0 * a0.x + f1 * a1.x + f2 * a2.x + f3 * a3.x) * inv;
        r.y = (f0 * a0.y + f1 * a1.y + f2 * a2.y + f3 * a3.y) * inv;
        r.z = (f0 * a0.z + f1 * a1.z + f2 * a2.z + f3 * a3.z) * inv;
        r.w = (f0 * a0.w + f1 * a1.w + f2 * a2.w + f3 * a3.w) * inv;
        ((ushort4*)(Xb + (size_t)b * KP + ND))[tid] =
            make_ushort4(f2bf(r.x), f2bf(r.y), f2bf(r.z), f2bf(r.w));
    }
}

// -------- Kernel 2: bf16 MFMA projection: out = Xb @ Wb^T + bias --------
__global__ __launch_bounds__(256, 1) void mfma_proj_kernel(
    const unsigned short* __restrict__ Xb,   // [NB][KP] bf16
    const unsigned short* __restrict__ Wb,   // [1024][KP] bf16
    const float* __restrict__ wb,            // [NH]
    float* __restrict__ out)                 // [NB][NH]
{
    __shared__ float red[64][65];

    const int tid  = threadIdx.x;
    const int wave = tid >> 6;
    const int lane = tid & 63;
    const int row0 = blockIdx.x * 64;
    const int col0 = blockIdx.y * 64;
    const int r    = lane & 15;
    const int g    = lane >> 4;

    const int kbase = wave * 512 + g * 8;
    const unsigned short* xp = Xb + (size_t)(row0 + r) * KP + kbase;
    const unsigned short* wp = Wb + (size_t)(col0 + r) * KP + kbase;

    f32x4 acc[4][4];
    #pragma unroll
    for (int mi = 0; mi < 4; ++mi)
        #pragma unroll
        for (int ni = 0; ni < 4; ++ni)
            acc[mi][ni] = (f32x4){0.f, 0.f, 0.f, 0.f};

    bf16x8 a_[4], b_[4], an[4], bn[4];
    #pragma unroll
    for (int i = 0; i < 4; ++i) {
        a_[i] = *(const bf16x8*)(xp + (size_t)i * 16 * KP);
        b_[i] = *(const bf16x8*)(wp + (size_t)i * 16 * KP);
    }

    #pragma unroll 1
    for (int ks = 0; ks < 16; ++ks) {
        if (ks + 1 < 16) {
            const unsigned short* xq = xp + (ks + 1) * 32;
            const unsigned short* wq = wp + (ks + 1) * 32;
            #pragma unroll
            for (int i = 0; i < 4; ++i) {
                an[i] = *(const bf16x8*)(xq + (size_t)i * 16 * KP);
                bn[i] = *(const bf16x8*)(wq + (size_t)i * 16 * KP);
            }
        }
        #pragma unroll
        for (int mi = 0; mi < 4; ++mi)
            #pragma unroll
            for (int ni = 0; ni < 4; ++ni)
                acc[mi][ni] = __builtin_amdgcn_mfma_f32_16x16x32_bf16(
                    a_[mi], b_[ni], acc[mi][ni], 0, 0, 0);
        #pragma unroll
        for (int i = 0; i < 4; ++i) { a_[i] = an[i]; b_[i] = bn[i]; }
    }

    // ---- cross-wave reduce (serialized, 4 phases) ----
    #pragma unroll
    for (int w = 0; w < 4; ++w) {
        if (wave == w) {
            #pragma unroll
            for (int mi = 0; mi < 4; ++mi)
                #pragma unroll
                for (int ni = 0; ni < 4; ++ni)
                    #pragma unroll
                    for (int j = 0; j < 4; ++j) {
                        int rr = mi * 16 + g * 4 + j;   // C/D: row=(lane>>4)*4+reg
                        int cc = ni * 16 + r;           // C/D: col=lane&15
                        float v = acc[mi][ni][j];
                        if (w == 0) red[rr][cc] = v;
                        else        red[rr][cc] += v;
                    }
        }
        __syncthreads();
    }

    // ---- store + bias ----
    const int cc = tid & 63;
    const int rg = tid >> 6;
    const int gc = col0 + cc;
    if (gc < NH) {
        float bias = wb[gc];
        #pragma unroll
        for (int i = 0; i < 16; ++i) {
            int rr = rg * 16 + i;
            out[(size_t)(row0 + rr) * NH + gc] = red[rr][cc] + bias;
        }
    }
}

extern "C" void kernel_launch(void* const* d_in, const int* in_sizes, int n_in,
                              void* d_out, int out_size, void* d_ws, size_t ws_size,
                              hipStream_t stream) {
    const float* hc           = (const float*)d_in[0];
    const float* ho           = (const float*)d_in[1];
    const unsigned char* mask = (const unsigned char*)d_in[2];
    const float* Wa_w         = (const float*)d_in[3];
    const float* Wa_b         = (const float*)d_in[4];
    const float* Wc_w         = (const float*)d_in[5];
    const float* Wc_b         = (const float*)d_in[6];
    float* out = (float*)d_out;

    unsigned short* Xb = (unsigned short*)d_ws;                       // 1024*2048 bf16 = 4 MB
    unsigned short* Wb = (unsigned short*)d_ws + (size_t)NB * KP;     // 1024*2048 bf16 = 4 MB

    prep_kernel<<<2048, 256, 0, stream>>>(hc, Wc_w, Xb, Wb);
    attn_pool_kernel<<<NB, 256, 0, stream>>>(ho, mask, Wa_w, Wa_b, Xb);
    mfma_proj_kernel<<<dim3(16, 16), 256, 0, stream>>>(Xb, Wb, Wc_b, out);
}